// Round 12
// baseline (125.629 us; speedup 1.0000x reference)
//
#include <hip/hip_runtime.h>
#include <hip/hip_bf16.h>
#include <stdint.h>

#define DIM     1024
#define DINNER  2048
#define BATCH   4096
#define LN_EPS  1e-5f

typedef unsigned short u16;
using f32x4  = __attribute__((ext_vector_type(4))) float;
using bf16x8 = __attribute__((ext_vector_type(8))) __bf16;

__device__ __forceinline__ float bf2f(u16 h) {
    union { unsigned u; float f; } v; v.u = ((unsigned)h) << 16; return v.f;
}
__device__ __forceinline__ u16 f2bf(float f) {
    union { float f; unsigned u; } v; v.f = f;
    unsigned r = v.u + 0x7fffu + ((v.u >> 16) & 1u);
    return (u16)(r >> 16);
}
__device__ __forceinline__ float silu_f(float x) {
    return x / (1.f + __expf(-x));
}

#define AS1 __attribute__((address_space(1)))
#define AS3 __attribute__((address_space(3)))

__device__ __forceinline__ unsigned lds_u32(const void* p) {
    return (unsigned)(unsigned long long)(const AS3 void*)p;
}

// ---------------- fused weight-cvt + LayerNorm ----------------
__global__ __launch_bounds__(256)
void cvt_ln(const float* __restrict__ x, const float* __restrict__ gamma,
            const float* __restrict__ beta, u16* __restrict__ xn,
            const float4* __restrict__ s0, ushort4* __restrict__ d0, int n0,
            const float4* __restrict__ s1, ushort4* __restrict__ d1, int n1,
            const float4* __restrict__ s2, ushort4* __restrict__ d2, int n2,
            const float4* __restrict__ s3, ushort4* __restrict__ d3, int n3)
{
    const int t = threadIdx.x;
    if (blockIdx.x < BATCH) {
        const int row = blockIdx.x;
        float4 v = ((const float4*)(x + (size_t)row * DIM))[t];
        float s1v = v.x + v.y + v.z + v.w;
        float s2v = v.x*v.x + v.y*v.y + v.z*v.z + v.w*v.w;
        #pragma unroll
        for (int o = 32; o > 0; o >>= 1) {
            s1v += __shfl_down(s1v, o);
            s2v += __shfl_down(s2v, o);
        }
        __shared__ float red[8];
        __shared__ float mv[2];
        const int w = t >> 6, l = t & 63;
        if (l == 0) { red[w] = s1v; red[4 + w] = s2v; }
        __syncthreads();
        if (t == 0) {
            float a = red[0] + red[1] + red[2] + red[3];
            float b = red[4] + red[5] + red[6] + red[7];
            float mu = a * (1.f / DIM);
            float var = b * (1.f / DIM) - mu * mu;
            mv[0] = mu; mv[1] = rsqrtf(var + LN_EPS);
        }
        __syncthreads();
        const float mu = mv[0], rs = mv[1];
        float4 g  = ((const float4*)gamma)[t];
        float4 be = ((const float4*)beta)[t];
        ushort4 o = make_ushort4(
            f2bf((v.x - mu) * rs * g.x + be.x),
            f2bf((v.y - mu) * rs * g.y + be.y),
            f2bf((v.z - mu) * rs * g.z + be.z),
            f2bf((v.w - mu) * rs * g.w + be.w));
        *(ushort4*)(xn + (size_t)row * DIM + t * 4) = o;
    } else {
        int i = (blockIdx.x - BATCH) * 256 + t;
        const int stride = (gridDim.x - BATCH) * 256;
        const int total = n0 + n1 + n2 + n3;
        for (; i < total; i += stride) {
            int j = i; const float4* s; ushort4* d;
            if (j < n0) { s = s0; d = d0; }
            else { j -= n0;
                if (j < n1) { s = s1; d = d1; }
                else { j -= n1;
                    if (j < n2) { s = s2; d = d2; }
                    else { j -= n2; s = s3; d = d3; }
                }
            }
            float4 v = s[j];
            d[j] = make_ushort4(f2bf(v.x), f2bf(v.y), f2bf(v.z), f2bf(v.w));
        }
    }
}

// =============== 256x256 pipelined bt-GEMM (GEMM1, R8 structure) ===============
#define DSR(d, adr, OFFSTR) \
    asm volatile("ds_read_b128 %0, %1 offset:" OFFSTR : "=v"(d) : "v"(adr))
#define RD_A8(DST, A0, A1, S0, S1, S2, S3) do { \
    DSR(DST[0][0], A0, S0); DSR(DST[0][1], A1, S0); \
    DSR(DST[1][0], A0, S1); DSR(DST[1][1], A1, S1); \
    DSR(DST[2][0], A0, S2); DSR(DST[2][1], A1, S2); \
    DSR(DST[3][0], A0, S3); DSR(DST[3][1], A1, S3); } while (0)
#define RD_B4(DST, A0, A1, S0, S1) do { \
    DSR(DST[0][0], A0, S0); DSR(DST[0][1], A1, S0); \
    DSR(DST[1][0], A0, S1); DSR(DST[1][1], A1, S1); } while (0)

#define BC8(x) __builtin_bit_cast(bf16x8, x)
#define MF1(C, Av, Bv) C = __builtin_amdgcn_mfma_f32_16x16x32_bf16(BC8(Av), BC8(Bv), C, 0, 0, 0)

#define CL32_LO do { \
    _Pragma("unroll") for (int m = 0; m < 4; ++m) \
    _Pragma("unroll") for (int n = 0; n < 2; ++n) \
    _Pragma("unroll") for (int k = 0; k < 2; ++k) { \
        MF1(acc[m][n],     aLo[m][k], bC0[n][k]); \
        MF1(acc[m][n + 2], aLo[m][k], bC1[n][k]); } } while (0)
#define CL16_HI0 do { \
    _Pragma("unroll") for (int m = 0; m < 4; ++m) \
    _Pragma("unroll") for (int n = 0; n < 2; ++n) \
    _Pragma("unroll") for (int k = 0; k < 2; ++k) \
        MF1(acc[4 + m][n], aHi[m][k], bC0[n][k]); } while (0)
#define CL16_HI1 do { \
    _Pragma("unroll") for (int m = 0; m < 4; ++m) \
    _Pragma("unroll") for (int n = 0; n < 2; ++n) \
    _Pragma("unroll") for (int k = 0; k < 2; ++k) \
        MF1(acc[4 + m][n + 2], aHi[m][k], bC1[n][k]); } while (0)

#define WAIT_LGKM8 do { asm volatile("s_waitcnt lgkmcnt(8)" ::: "memory"); \
    __builtin_amdgcn_sched_barrier(0); } while (0)
#define WAIT_LGKM0 do { asm volatile("s_waitcnt lgkmcnt(0)" ::: "memory"); \
    __builtin_amdgcn_sched_barrier(0); } while (0)

#define TILE_BODY(CA0, CA1, NA0, NA1, NB0, NB1, SDA0, SDA1, SDB0, SDB1, KT) do { \
    RD_A8(aHi, CA0, CA1, "8192", "10240", "12288", "14336"); \
    WAIT_LGKM8; \
    __builtin_amdgcn_s_setprio(1); CL32_LO; __builtin_amdgcn_s_setprio(0); \
    WAIT_LGKM0; \
    asm volatile("s_waitcnt vmcnt(0)" ::: "memory"); \
    __builtin_amdgcn_s_barrier(); \
    stage(SDB0, Bb, KT); stage(SDB1, BbH, KT); \
    stage(SDA0, Ab, KT); stage(SDA1, AbH, KT); \
    __builtin_amdgcn_s_setprio(1); CL16_HI0; __builtin_amdgcn_s_setprio(0); \
    RD_B4(bC0, NB0, NB1, "0", "2048"); \
    RD_A8(aLo, NA0, NA1, "0", "2048", "4096", "6144"); \
    __builtin_amdgcn_s_setprio(1); CL16_HI1; __builtin_amdgcn_s_setprio(0); \
    RD_B4(bC1, NB0, NB1, "4096", "6144"); \
} while (0)

__global__ __launch_bounds__(512, 2)
void gemmP(const u16* __restrict__ A, const u16* __restrict__ B,
           int N, int K, int nkt,
           u16* __restrict__ dst0, u16* __restrict__ dst1,
           const float* __restrict__ conv_w, const float* __restrict__ conv_b)
{
    __shared__ __align__(16) u16 lds[2][4][8192];
    const int tid = threadIdx.x;
    const int wid = tid >> 6, l = tid & 63;
    const int wm = wid >> 2, wn = wid & 3;
    const int lr = l & 15, l16 = l >> 4;
    const int brow = blockIdx.y * 256, bcol = blockIdx.x * 256;

    const int sr = tid >> 3;
    const int skk = ((tid & 7) ^ (sr & 7)) * 8;
    const u16* Ab  = A + (size_t)(brow + sr) * K + skk;
    const u16* Bb  = B + (size_t)(bcol + sr) * K + skk;
    const u16* AbH = Ab + (size_t)128 * K;
    const u16* BbH = Bb + (size_t)128 * K;

    u16* const dA0h0 = &lds[0][0][tid * 8]; u16* const dA0h1 = &lds[0][1][tid * 8];
    u16* const dA1h0 = &lds[1][0][tid * 8]; u16* const dA1h1 = &lds[1][1][tid * 8];
    u16* const dB0h0 = &lds[0][2][tid * 8]; u16* const dB0h1 = &lds[0][3][tid * 8];
    u16* const dB1h0 = &lds[1][2][tid * 8]; u16* const dB1h1 = &lds[1][3][tid * 8];

    const unsigned cxb0 = (unsigned)(((0 + l16) ^ (l & 7)) * 16);
    const unsigned cxb1 = (unsigned)(((4 + l16) ^ (l & 7)) * 16);
    const unsigned aB0 = lds_u32(&lds[0][wm][0]) + (unsigned)(lr * 128);
    const unsigned bB0 = lds_u32(&lds[0][2 + (wn >> 1)][0]) + (unsigned)((wn & 1) * 8192 + lr * 128);
    const unsigned adA00 = aB0 + cxb0, adA01 = aB0 + cxb1;
    const unsigned adA10 = adA00 + 65536, adA11 = adA01 + 65536;
    const unsigned adB00 = bB0 + cxb0, adB01 = bB0 + cxb1;
    const unsigned adB10 = adB00 + 65536, adB11 = adB01 + 65536;

    f32x4 acc[8][4] = {};
    float4 aLo[4][2], aHi[4][2], bC0[2][2], bC1[2][2];

    auto stage = [&](u16* dst, const u16* srcrow, int kt) {
        const u16* s = srcrow + (size_t)kt * 64;
        __builtin_amdgcn_global_load_lds((const AS1 void*)s, (AS3 void*)dst, 16, 0, 0);
        __builtin_amdgcn_global_load_lds((const AS1 void*)(s + (size_t)64 * K),
                                         (AS3 void*)(dst + 4096), 16, 0, 0);
    };

    stage(dB0h0, Bb, 0);  stage(dB0h1, BbH, 0);
    stage(dA0h0, Ab, 0);  stage(dA0h1, AbH, 0);
    stage(dB1h0, Bb, 1);  stage(dB1h1, BbH, 1);
    stage(dA1h0, Ab, 1);  stage(dA1h1, AbH, 1);
    asm volatile("s_waitcnt vmcnt(8)" ::: "memory");
    __builtin_amdgcn_s_barrier();
    RD_B4(bC0, adB00, adB01, "0", "2048");
    RD_B4(bC1, adB00, adB01, "4096", "6144");
    RD_A8(aLo, adA00, adA01, "0", "2048", "4096", "6144");

    const int niter = nkt >> 1;
    for (int i = 0; i < niter; ++i) {
        const int T = 2 * i;
        const int k2 = (T + 2 < nkt) ? T + 2 : nkt - 1;
        const int k3 = (T + 3 < nkt) ? T + 3 : nkt - 1;
        TILE_BODY(adA00, adA01, adA10, adA11, adB10, adB11,
                  dA0h0, dA0h1, dB0h0, dB0h1, k2);
        TILE_BODY(adA10, adA11, adA00, adA01, adB00, adB01,
                  dA1h0, dA1h1, dB1h0, dB1h1, k3);
    }

    asm volatile("s_waitcnt vmcnt(0) lgkmcnt(0)" ::: "memory");
    __builtin_amdgcn_s_barrier();

    float cb[4], cw[4];
    const bool isxc = (bcol < DINNER);
    if (isxc) {
        #pragma unroll
        for (int n = 0; n < 4; ++n) {
            const int cg = bcol + wn * 64 + n * 16 + lr;
            cb[n] = conv_b[cg]; cw[n] = conv_w[cg * 4 + 3];
        }
    }
    // epilogue LDS bounce; XOR granule = 16 u16 = 32B (bank-effective)
    u16* eb = &lds[0][0][0];
    #pragma unroll
    for (int m = 0; m < 8; ++m)
        #pragma unroll
        for (int n = 0; n < 4; ++n)
            #pragma unroll
            for (int r = 0; r < 4; ++r) {
                const int rl = wm * 128 + m * 16 + l16 * 4 + r;
                const int cl = wn * 64 + n * 16 + lr;
                float v = acc[m][n][r];
                v = isxc ? silu_f(cb[n] + cw[n] * v) : silu_f(v);
                eb[rl * 256 + (cl ^ (((rl >> 2) & 3) << 4))] = f2bf(v);
            }
    __syncthreads();

    u16* base = isxc ? (dst0 + bcol) : (dst1 + (bcol - DINNER));
    #pragma unroll
    for (int it = 0; it < 16; ++it) {
        const int idx = it * 4096 + tid * 8;
        const int r = idx >> 8, c = idx & 255;
        uint4 v = *(const uint4*)(eb + r * 256 + (c ^ (((r >> 2) & 3) << 4)));
        *(uint4*)(base + (size_t)(brow + r) * DINNER + c) = v;
    }
}

// ---------------- GEMM2 split-K: P[ks][4096][96] partials (fp32, row-major) ----------------
__global__ __launch_bounds__(256)
void gemm_xproj(const u16* __restrict__ xcb, const u16* __restrict__ Wx,
                float* __restrict__ P)
{
    __shared__ __align__(16) u16 Xs[64 * 64];
    __shared__ __align__(16) u16 Ws[96 * 64];
    const int t = threadIdx.x, w = t >> 6, l = t & 63;
    const int brow = blockIdx.x * 64;
    const int ks = blockIdx.y;
    const int lr = l & 15, l16 = l >> 4;
    const int skk = ((l & 7) ^ (l >> 3)) * 8;
    const u16* Xbase = xcb + (size_t)(brow + (l >> 3)) * DINNER + skk;
    const u16* Wbase = Wx + (size_t)(l >> 3) * DINNER + skk;

    f32x4 acc[6] = {};
    const int kend = ks * 512 + 512;
    for (int k0 = ks * 512; k0 < kend; k0 += 64) {
        #pragma unroll
        for (int c = 0; c < 2; ++c) {
            const int seg = c * 4 + w;
            __builtin_amdgcn_global_load_lds(
                (const AS1 void*)(Xbase + (size_t)seg * 8 * DINNER + k0),
                (AS3 void*)(&Xs[seg * 512]), 16, 0, 0);
        }
        #pragma unroll
        for (int c = 0; c < 3; ++c) {
            const int seg = c * 4 + w;
            __builtin_amdgcn_global_load_lds(
                (const AS1 void*)(Wbase + (size_t)seg * 8 * DINNER + k0),
                (AS3 void*)(&Ws[seg * 512]), 16, 0, 0);
        }
        __syncthreads();
        #pragma unroll
        for (int kk = 0; kk < 2; ++kk) {
            const int ra = w * 16 + lr;
            bf16x8 av = *(const bf16x8*)(&Xs[ra * 64 + (((kk * 4 + l16) ^ (ra & 7)) * 8)]);
            #pragma unroll
            for (int n = 0; n < 6; ++n) {
                const int rb = n * 16 + lr;
                bf16x8 bv = *(const bf16x8*)(&Ws[rb * 64 + (((kk * 4 + l16) ^ (rb & 7)) * 8)]);
                acc[n] = __builtin_amdgcn_mfma_f32_16x16x32_bf16(av, bv, acc[n], 0, 0, 0);
            }
        }
        __syncthreads();
    }
    // coalesced write: lanes (lr) vary col -> consecutive floats
    #pragma unroll
    for (int n = 0; n < 6; ++n)
        #pragma unroll
        for (int r = 0; r < 4; ++r) {
            const int row = brow + w * 16 + l16 * 4 + r;
            const int col = n * 16 + lr;
            P[((size_t)ks * BATCH + row) * 96 + col] = acc[n][r];
        }
}

// ---------------- finish (split, 96 blocks): sum partials -> dtb, s halves ----------------
// P layout [ks][4096][96]; per-thread contiguous float4 reads.
__global__ __launch_bounds__(256)
void finish_split(const float* __restrict__ P, u16* __restrict__ dtb,
                  float* __restrict__ s0, float* __restrict__ s1)
{
    const int b = blockIdx.x * 256 + threadIdx.x;
    const int y = blockIdx.y;
    if (y < 4) {
        const int c0 = y * 16;
        float v[16];
        #pragma unroll
        for (int j = 0; j < 4; ++j) {
            float4 a0 = *(const float4*)(P + ((size_t)0 * BATCH + b) * 96 + c0 + j * 4);
            float4 a1 = *(const float4*)(P + ((size_t)1 * BATCH + b) * 96 + c0 + j * 4);
            float4 a2 = *(const float4*)(P + ((size_t)2 * BATCH + b) * 96 + c0 + j * 4);
            float4 a3 = *(const float4*)(P + ((size_t)3 * BATCH + b) * 96 + c0 + j * 4);
            v[j * 4 + 0] = a0.x + a1.x + a2.x + a3.x;
            v[j * 4 + 1] = a0.y + a1.y + a2.y + a3.y;
            v[j * 4 + 2] = a0.z + a1.z + a2.z + a3.z;
            v[j * 4 + 3] = a0.w + a1.w + a2.w + a3.w;
        }
        uint4 o0, o1;
        unsigned* p0 = (unsigned*)&o0;
        unsigned* p1 = (unsigned*)&o1;
        #pragma unroll
        for (int k = 0; k < 4; ++k) {
            p0[k] = (unsigned)f2bf(v[2 * k])     | ((unsigned)f2bf(v[2 * k + 1]) << 16);
            p1[k] = (unsigned)f2bf(v[8 + 2 * k]) | ((unsigned)f2bf(v[8 + 2 * k + 1]) << 16);
        }
        *(uint4*)(dtb + (size_t)b * 64 + c0)     = o0;
        *(uint4*)(dtb + (size_t)b * 64 + c0 + 8) = o1;
    } else {
        const int n0 = (y == 4) ? 0 : 8;
        float Bv[8] = {}, Cv[8] = {};
        #pragma unroll
        for (int ks = 0; ks < 4; ++ks) {
            const float* base = P + ((size_t)ks * BATCH + b) * 96;
            float4 b0 = *(const float4*)(base + 64 + n0);
            float4 b1 = *(const float4*)(base + 64 + n0 + 4);
            float4 c0v = *(const float4*)(base + 80 + n0);
            float4 c1v = *(const float4*)(base + 80 + n0 + 4);
            Bv[0] += b0.x; Bv[1] += b0.y; Bv[2] += b0.z; Bv[3] += b0.w;
            Bv[4] += b1.x; Bv[5] += b1.y; Bv[6] += b1.z; Bv[7] += b1.w;
            Cv[0] += c0v.x; Cv[1] += c0v.y; Cv[2] += c0v.z; Cv[3] += c0v.w;
            Cv[4] += c1v.x; Cv[5] += c1v.y; Cv[6] += c1v.z; Cv[7] += c1v.w;
        }
        float s = 0.f;
        #pragma unroll
        for (int n = 0; n < 8; ++n) s += Bv[n] * Cv[n];
        ((y == 4) ? s0 : s1)[b] = s;
    }
}

// ---------------- GEMM3 + y epilogue (vectorized via bf16-dt LDS bounce) ----------------
__global__ __launch_bounds__(256)
void gemm_dt_y(const u16* __restrict__ dtb, const u16* __restrict__ Wdt,
               const float* __restrict__ b_dt, const float* __restrict__ Dskip,
               const float* __restrict__ s0, const float* __restrict__ s1,
               const u16* __restrict__ xcb, const u16* __restrict__ szb,
               u16* __restrict__ y)
{
    __shared__ __align__(16) u16 Ds[64 * 64];
    __shared__ __align__(16) u16 Ws[128 * 64];
    __shared__ __align__(16) u16 dts[64 * 128];
    const int t = threadIdx.x, w = t >> 6, l = t & 63;
    const int wr = w >> 1, wc = w & 1;
    const int brow = blockIdx.y * 64;
    const int bcol = blockIdx.x * 128;
    const int lr = l & 15, l16 = l >> 4;
    const int skk = ((l & 7) ^ (l >> 3)) * 8;

    {
        const u16* Dbase = dtb + (size_t)(brow + (l >> 3)) * 64 + skk;
        const u16* Wbase = Wdt + (size_t)(bcol + (l >> 3)) * 64 + skk;
        #pragma unroll
        for (int c = 0; c < 2; ++c) {
            const int seg = c * 4 + w;
            __builtin_amdgcn_global_load_lds(
                (const AS1 void*)(Dbase + (size_t)seg * 8 * 64),
                (AS3 void*)(&Ds[seg * 512]), 16, 0, 0);
        }
        #pragma unroll
        for (int c = 0; c < 4; ++c) {
            const int seg = c * 4 + w;
            __builtin_amdgcn_global_load_lds(
                (const AS1 void*)(Wbase + (size_t)seg * 8 * 64),
                (AS3 void*)(&Ws[seg * 512]), 16, 0, 0);
        }
    }
    __syncthreads();

    f32x4 acc[2][4] = {};
    #pragma unroll
    for (int kk = 0; kk < 2; ++kk) {
        bf16x8 av[2], bv[4];
        #pragma unroll
        for (int m = 0; m < 2; ++m) {
            const int r = wr * 32 + m * 16 + lr;
            av[m] = *(const bf16x8*)(&Ds[r * 64 + (((kk * 4 + l16) ^ (r & 7)) * 8)]);
        }
        #pragma unroll
        for (int n = 0; n < 4; ++n) {
            const int r = wc * 64 + n * 16 + lr;
            bv[n] = *(const bf16x8*)(&Ws[r * 64 + (((kk * 4 + l16) ^ (r & 7)) * 8)]);
        }
        #pragma unroll
        for (int m = 0; m < 2; ++m)
            #pragma unroll
            for (int n = 0; n < 4; ++n)
                acc[m][n] = __builtin_amdgcn_mfma_f32_16x16x32_bf16(av[m], bv[n], acc[m][n], 0, 0, 0);
    }

    #pragma unroll
    for (int m = 0; m < 2; ++m)
        #pragma unroll
        for (int n = 0; n < 4; ++n)
            #pragma unroll
            for (int r = 0; r < 4; ++r) {
                const int row = wr * 32 + m * 16 + l16 * 4 + r;
                const int col = wc * 64 + n * 16 + lr;
                float v = acc[m][n][r] + b_dt[bcol + col];
                float dt = (v > 20.f) ? v : log1pf(__expf(v));
                dts[row * 128 + (col ^ ((row & 7) << 4))] = f2bf(dt);
            }
    __syncthreads();

    const int rlo = t >> 4;
    const int cg  = (t & 15) * 8;
    #pragma unroll
    for (int rr = 0; rr < 4; ++rr) {
        const int row = rr * 16 + rlo;
        const int grow = brow + row;
        const float sr = s0[grow] + s1[grow];
        uint4 dv = *(const uint4*)(&dts[row * 128 + ((cg ^ ((row & 7) << 4)))]);
        uint4 xv = *(const uint4*)(xcb + (size_t)grow * DINNER + bcol + cg);
        uint4 zv = *(const uint4*)(szb + (size_t)grow * DINNER + bcol + cg);
        float4 D0 = *(const float4*)(Dskip + bcol + cg);
        float4 D1 = *(const float4*)(Dskip + bcol + cg + 4);
        const float* Dp = &D0.x;
        uint4 ov;
        unsigned* op = (unsigned*)&ov;
        #pragma unroll
        for (int k = 0; k < 4; ++k) {
            unsigned du = ((const unsigned*)&dv)[k];
            unsigned xu = ((const unsigned*)&xv)[k];
            unsigned zu = ((const unsigned*)&zv)[k];
            float Da = (k < 2) ? Dp[2 * k]     : (&D1.x)[2 * (k - 2)];
            float Db = (k < 2) ? Dp[2 * k + 1] : (&D1.x)[2 * (k - 2) + 1];
            float y0 = (bf2f((u16)du) * sr + Da) * bf2f((u16)xu) * bf2f((u16)zu);
            float y1 = (bf2f((u16)(du >> 16)) * sr + Db) * bf2f((u16)(xu >> 16)) * bf2f((u16)(zu >> 16));
            op[k] = (unsigned)f2bf(y0) | ((unsigned)f2bf(y1) << 16);
        }
        *(uint4*)(y + (size_t)grow * DINNER + bcol + cg) = ov;
    }
}

// =============== GEMM4: 64x128 tile, direct fp32 out, dbuf counted vmcnt ===============
__global__ __launch_bounds__(256, 2)
void gemm4n(const u16* __restrict__ A, const u16* __restrict__ Bm,
            float* __restrict__ out)
{
    __shared__ __align__(16) u16 lds[2][12288];
    const int t = threadIdx.x, w = t >> 6, l = t & 63;
    const int wr = w >> 1, wc = w & 1;
    const int lr = l & 15, l16 = l >> 4;

    const int lin = blockIdx.y * 8 + blockIdx.x;
    const int xcd = lin & 7, q = lin >> 3;
    const int by = xcd * 8 + (q >> 3);
    const int bx = q & 7;
    const int brow = by * 64, bcol = bx * 128;
    const int K = DINNER, nkt = 32;

    auto stage = [&](int buf, int kt) {
        #pragma unroll
        for (int c = 0; c < 2; ++c) {
            const int o = c * 256 + t;
            const int sr = o >> 3;
            const int sc = (o & 7) ^ (sr & 7);
            __builtin_amdgcn_global_load_lds(
                (const AS1 void*)(A + (size_t)(brow + sr) * K + kt * 64 + sc * 8),
                (AS3 void*)(&lds[buf][o * 8]), 16, 0, 0);
        }
        #pragma unroll
        for (int c = 0; c < 4; ++c) {
            const int o = c * 256 + t;
            const int sr = o >> 3;
            const int sc = (o & 7) ^ (sr & 7);
            __builtin_amdgcn_global_load_lds(
                (const AS1 void*)(Bm + (size_t)(bcol + sr) * K + kt * 64 + sc * 8),
                (AS3 void*)(&lds[buf][4096 + o * 8]), 16, 0, 0);
        }
    };

    f32x4 acc[2][4] = {};

    stage(0, 0);
    stage(1, 1);
    asm volatile("s_waitcnt vmcnt(6)" ::: "memory");
    __builtin_amdgcn_s_barrier();

    for (int kt = 0; kt < nkt; ++kt) {
        const int cur = kt & 1;
        #pragma unroll
        for (int kk = 0; kk < 2; ++kk) {
            bf16x8 af[2], bf[4];
            #pragma unroll
            for (int m = 0; m < 2; ++m) {
                const int r = wr * 32 + m * 16 + lr;
                af[m] = *(const bf16x8*)(&lds[cur][r * 64 + (((kk * 4 + l16) ^ (r & 7)) * 8)]);
            }
            #pragma unroll
            for (int n = 0; n < 4; ++n) {
                const int r = wc * 64 + n * 16 + lr;
                bf[n] = *(const bf16x8*)(&lds[cur][4096 + r * 64 + (((kk * 4 + l16) ^ (r & 7)) * 8)]);
            }
            #pragma unroll
            for (int m = 0; m < 2; ++m)
                #pragma unroll
                for (int n = 0; n < 4; ++n)
                    acc[m][n] = __builtin_amdgcn_mfma_f32_16x16x32_bf16(af[m], bf[n], acc[m][n], 0, 0, 0);
        }
        __builtin_amdgcn_sched_barrier(0);
        __builtin_amdgcn_s_barrier();
        const int t2 = (kt + 2 < nkt) ? kt + 2 : nkt - 1;
        stage(cur, t2);
        asm volatile("s_waitcnt vmcnt(6)" ::: "memory");
        __builtin_amdgcn_sched_barrier(0);
        __builtin_amdgcn_s_barrier();
    }

    asm volatile("s_waitcnt vmcnt(0) lgkmcnt(0)" ::: "memory");
    __builtin_amdgcn_s_barrier();

    float* eb = (float*)&lds[0][0];
    #pragma unroll
    for (int m = 0; m < 2; ++m)
        #pragma unroll
        for (int n = 0; n < 4; ++n)
            #pragma unroll
            for (int r = 0; r < 4; ++r) {
                const int row = wr * 32 + m * 16 + l16 * 4 + r;
                const int col = wc * 64 + n * 16 + lr;
                eb[row * 128 + (col ^ ((row & 7) << 2))] = acc[m][n][r];
            }
    __syncthreads();
    #pragma unroll
    for (int it = 0; it < 8; ++it) {
        const int idx = it * 1024 + t * 4;
        const int row = idx >> 7, col = idx & 127;
        float4 v = *(const float4*)(eb + row * 128 + ((col ^ ((row & 7) << 2))));
        *(float4*)(out + (size_t)(brow + row) * DIM + bcol + col) = v;
    }
}

extern "C" void kernel_launch(void* const* d_in, const int* in_sizes, int n_in,
                              void* d_out, int out_size, void* d_ws, size_t ws_size,
                              hipStream_t stream) {
    const float* x      = (const float*)d_in[0];
    const float* ln_g   = (const float*)d_in[1];
    const float* ln_b   = (const float*)d_in[2];
    const float* W_in   = (const float*)d_in[3];
    const float* conv_w = (const float*)d_in[4];
    const float* conv_b = (const float*)d_in[5];
    const float* W_xp   = (const float*)d_in[6];
    const float* W_dt   = (const float*)d_in[7];
    const float* b_dt   = (const float*)d_in[8];
    // d_in[9] = A_log : dead (L=1, h0=0)
    const float* Dskip  = (const float*)d_in[10];
    const float* W_out  = (const float*)d_in[11];
    float* out = (float*)d_out;

    char* ws = (char*)d_ws;
    const size_t MB = 1u << 20;
    u16*  W_in_b  = (u16*)(ws);                   // 8MB
    u16*  xn      = (u16*)(ws + 8 * MB);          // 8MB
    u16*  xcb     = (u16*)(ws + 16 * MB);         // 16MB
    u16*  szb     = (u16*)(ws + 32 * MB);         // 16MB
    float* Pxp    = (float*)(ws + 48 * MB);       // 6MB
    u16*  W_xp_b  = (u16*)(ws + 55 * MB);         // 384KB
    u16*  W_dt_b  = (u16*)(ws + 56 * MB);         // 256KB
    u16*  dtb     = (u16*)(ws + 57 * MB);         // 512KB
    float* sbuf0  = (float*)(ws + 58 * MB);       // 16KB
    float* sbuf1  = (float*)(ws + 59 * MB);       // 16KB
    u16*  W_out_b = (u16*)(ws + 64 * MB);         // 4MB
    u16*  yb      = (u16*)(ws + 68 * MB);         // 16MB

    // 1) weight cvt + LN
    cvt_ln<<<BATCH + 2048, 256, 0, stream>>>(
        x, ln_g, ln_b, xn,
        (const float4*)W_in,  (ushort4*)W_in_b,  (2 * DINNER * DIM) / 4,
        (const float4*)W_out, (ushort4*)W_out_b, (DIM * DINNER) / 4,
        (const float4*)W_xp,  (ushort4*)W_xp_b,  (96 * DINNER) / 4,
        (const float4*)W_dt,  (ushort4*)W_dt_b,  (DINNER * 64) / 4);

    // 2) GEMM1: xz = xn @ W_in^T (fused conv+silu -> xc, sz)
    gemmP<<<dim3(4096 / 256, BATCH / 256, 1), 512, 0, stream>>>(
        xn, W_in_b, 4096, DIM, DIM / 64, xcb, szb, conv_w, conv_b);

    // 3) GEMM2 (split-K x4): partials, row-major [ks][batch][96]
    gemm_xproj<<<dim3(BATCH / 64, 4), 256, 0, stream>>>(xcb, W_xp_b, Pxp);

    // 4) finish (96 blocks): dtb bf16 + s halves
    finish_split<<<dim3(16, 6), 256, 0, stream>>>(Pxp, dtb, sbuf0, sbuf1);

    // 5) GEMM3 + epilogue: y
    gemm_dt_y<<<dim3(DINNER / 128, BATCH / 64), 256, 0, stream>>>(
        dtb, W_dt_b, b_dt, Dskip, sbuf0, sbuf1, xcb, szb, yb);

    // 6) GEMM4: out = y @ W_out^T (direct fp32, 64x128 tiles)
    gemm4n<<<dim3(DIM / 128, BATCH / 64), 256, 0, stream>>>(yb, W_out_b, out);
}

// Round 13
// 118.974 us; speedup vs baseline: 1.0559x; 1.0559x over previous
//
#include <hip/hip_runtime.h>
#include <hip/hip_bf16.h>
#include <stdint.h>

#define DIM     1024
#define DINNER  2048
#define BATCH   4096
#define LN_EPS  1e-5f

typedef unsigned short u16;
using f32x4  = __attribute__((ext_vector_type(4))) float;
using bf16x8 = __attribute__((ext_vector_type(8))) __bf16;

__device__ __forceinline__ float bf2f(u16 h) {
    union { unsigned u; float f; } v; v.u = ((unsigned)h) << 16; return v.f;
}
__device__ __forceinline__ u16 f2bf(float f) {
    union { float f; unsigned u; } v; v.f = f;
    unsigned r = v.u + 0x7fffu + ((v.u >> 16) & 1u);
    return (u16)(r >> 16);
}
__device__ __forceinline__ float silu_f(float x) {
    return x / (1.f + __expf(-x));
}

#define AS1 __attribute__((address_space(1)))
#define AS3 __attribute__((address_space(3)))

__device__ __forceinline__ unsigned lds_u32(const void* p) {
    return (unsigned)(unsigned long long)(const AS3 void*)p;
}

// ---------------- fused weight-cvt + LayerNorm ----------------
__global__ __launch_bounds__(256)
void cvt_ln(const float* __restrict__ x, const float* __restrict__ gamma,
            const float* __restrict__ beta, u16* __restrict__ xn,
            const float4* __restrict__ s0, ushort4* __restrict__ d0, int n0,
            const float4* __restrict__ s1, ushort4* __restrict__ d1, int n1,
            const float4* __restrict__ s2, ushort4* __restrict__ d2, int n2,
            const float4* __restrict__ s3, ushort4* __restrict__ d3, int n3)
{
    const int t = threadIdx.x;
    if (blockIdx.x < BATCH) {
        const int row = blockIdx.x;
        float4 v = ((const float4*)(x + (size_t)row * DIM))[t];
        float s1v = v.x + v.y + v.z + v.w;
        float s2v = v.x*v.x + v.y*v.y + v.z*v.z + v.w*v.w;
        #pragma unroll
        for (int o = 32; o > 0; o >>= 1) {
            s1v += __shfl_down(s1v, o);
            s2v += __shfl_down(s2v, o);
        }
        __shared__ float red[8];
        __shared__ float mv[2];
        const int w = t >> 6, l = t & 63;
        if (l == 0) { red[w] = s1v; red[4 + w] = s2v; }
        __syncthreads();
        if (t == 0) {
            float a = red[0] + red[1] + red[2] + red[3];
            float b = red[4] + red[5] + red[6] + red[7];
            float mu = a * (1.f / DIM);
            float var = b * (1.f / DIM) - mu * mu;
            mv[0] = mu; mv[1] = rsqrtf(var + LN_EPS);
        }
        __syncthreads();
        const float mu = mv[0], rs = mv[1];
        float4 g  = ((const float4*)gamma)[t];
        float4 be = ((const float4*)beta)[t];
        ushort4 o = make_ushort4(
            f2bf((v.x - mu) * rs * g.x + be.x),
            f2bf((v.y - mu) * rs * g.y + be.y),
            f2bf((v.z - mu) * rs * g.z + be.z),
            f2bf((v.w - mu) * rs * g.w + be.w));
        *(ushort4*)(xn + (size_t)row * DIM + t * 4) = o;
    } else {
        int i = (blockIdx.x - BATCH) * 256 + t;
        const int stride = (gridDim.x - BATCH) * 256;
        const int total = n0 + n1 + n2 + n3;
        for (; i < total; i += stride) {
            int j = i; const float4* s; ushort4* d;
            if (j < n0) { s = s0; d = d0; }
            else { j -= n0;
                if (j < n1) { s = s1; d = d1; }
                else { j -= n1;
                    if (j < n2) { s = s2; d = d2; }
                    else { j -= n2; s = s3; d = d3; }
                }
            }
            float4 v = s[j];
            d[j] = make_ushort4(f2bf(v.x), f2bf(v.y), f2bf(v.z), f2bf(v.w));
        }
    }
}

// =============== 256x256 pipelined bt-GEMM (GEMM1, R8 structure) ===============
#define DSR(d, adr, OFFSTR) \
    asm volatile("ds_read_b128 %0, %1 offset:" OFFSTR : "=v"(d) : "v"(adr))
#define RD_A8(DST, A0, A1, S0, S1, S2, S3) do { \
    DSR(DST[0][0], A0, S0); DSR(DST[0][1], A1, S0); \
    DSR(DST[1][0], A0, S1); DSR(DST[1][1], A1, S1); \
    DSR(DST[2][0], A0, S2); DSR(DST[2][1], A1, S2); \
    DSR(DST[3][0], A0, S3); DSR(DST[3][1], A1, S3); } while (0)
#define RD_B4(DST, A0, A1, S0, S1) do { \
    DSR(DST[0][0], A0, S0); DSR(DST[0][1], A1, S0); \
    DSR(DST[1][0], A0, S1); DSR(DST[1][1], A1, S1); } while (0)

#define BC8(x) __builtin_bit_cast(bf16x8, x)
#define MF1(C, Av, Bv) C = __builtin_amdgcn_mfma_f32_16x16x32_bf16(BC8(Av), BC8(Bv), C, 0, 0, 0)

#define CL32_LO do { \
    _Pragma("unroll") for (int m = 0; m < 4; ++m) \
    _Pragma("unroll") for (int n = 0; n < 2; ++n) \
    _Pragma("unroll") for (int k = 0; k < 2; ++k) { \
        MF1(acc[m][n],     aLo[m][k], bC0[n][k]); \
        MF1(acc[m][n + 2], aLo[m][k], bC1[n][k]); } } while (0)
#define CL16_HI0 do { \
    _Pragma("unroll") for (int m = 0; m < 4; ++m) \
    _Pragma("unroll") for (int n = 0; n < 2; ++n) \
    _Pragma("unroll") for (int k = 0; k < 2; ++k) \
        MF1(acc[4 + m][n], aHi[m][k], bC0[n][k]); } while (0)
#define CL16_HI1 do { \
    _Pragma("unroll") for (int m = 0; m < 4; ++m) \
    _Pragma("unroll") for (int n = 0; n < 2; ++n) \
    _Pragma("unroll") for (int k = 0; k < 2; ++k) \
        MF1(acc[4 + m][n + 2], aHi[m][k], bC1[n][k]); } while (0)

#define WAIT_LGKM8 do { asm volatile("s_waitcnt lgkmcnt(8)" ::: "memory"); \
    __builtin_amdgcn_sched_barrier(0); } while (0)
#define WAIT_LGKM0 do { asm volatile("s_waitcnt lgkmcnt(0)" ::: "memory"); \
    __builtin_amdgcn_sched_barrier(0); } while (0)

#define TILE_BODY(CA0, CA1, NA0, NA1, NB0, NB1, SDA0, SDA1, SDB0, SDB1, KT) do { \
    RD_A8(aHi, CA0, CA1, "8192", "10240", "12288", "14336"); \
    WAIT_LGKM8; \
    __builtin_amdgcn_s_setprio(1); CL32_LO; __builtin_amdgcn_s_setprio(0); \
    WAIT_LGKM0; \
    asm volatile("s_waitcnt vmcnt(0)" ::: "memory"); \
    __builtin_amdgcn_s_barrier(); \
    stage(SDB0, Bb, KT); stage(SDB1, BbH, KT); \
    stage(SDA0, Ab, KT); stage(SDA1, AbH, KT); \
    __builtin_amdgcn_s_setprio(1); CL16_HI0; __builtin_amdgcn_s_setprio(0); \
    RD_B4(bC0, NB0, NB1, "0", "2048"); \
    RD_A8(aLo, NA0, NA1, "0", "2048", "4096", "6144"); \
    __builtin_amdgcn_s_setprio(1); CL16_HI1; __builtin_amdgcn_s_setprio(0); \
    RD_B4(bC1, NB0, NB1, "4096", "6144"); \
} while (0)

__global__ __launch_bounds__(512, 2)
void gemmP(const u16* __restrict__ A, const u16* __restrict__ B,
           int N, int K, int nkt,
           u16* __restrict__ dst0, u16* __restrict__ dst1,
           const float* __restrict__ conv_w, const float* __restrict__ conv_b)
{
    __shared__ __align__(16) u16 lds[2][4][8192];
    const int tid = threadIdx.x;
    const int wid = tid >> 6, l = tid & 63;
    const int wm = wid >> 2, wn = wid & 3;
    const int lr = l & 15, l16 = l >> 4;
    const int brow = blockIdx.y * 256, bcol = blockIdx.x * 256;

    const int sr = tid >> 3;
    const int skk = ((tid & 7) ^ (sr & 7)) * 8;
    const u16* Ab  = A + (size_t)(brow + sr) * K + skk;
    const u16* Bb  = B + (size_t)(bcol + sr) * K + skk;
    const u16* AbH = Ab + (size_t)128 * K;
    const u16* BbH = Bb + (size_t)128 * K;

    u16* const dA0h0 = &lds[0][0][tid * 8]; u16* const dA0h1 = &lds[0][1][tid * 8];
    u16* const dA1h0 = &lds[1][0][tid * 8]; u16* const dA1h1 = &lds[1][1][tid * 8];
    u16* const dB0h0 = &lds[0][2][tid * 8]; u16* const dB0h1 = &lds[0][3][tid * 8];
    u16* const dB1h0 = &lds[1][2][tid * 8]; u16* const dB1h1 = &lds[1][3][tid * 8];

    const unsigned cxb0 = (unsigned)(((0 + l16) ^ (l & 7)) * 16);
    const unsigned cxb1 = (unsigned)(((4 + l16) ^ (l & 7)) * 16);
    const unsigned aB0 = lds_u32(&lds[0][wm][0]) + (unsigned)(lr * 128);
    const unsigned bB0 = lds_u32(&lds[0][2 + (wn >> 1)][0]) + (unsigned)((wn & 1) * 8192 + lr * 128);
    const unsigned adA00 = aB0 + cxb0, adA01 = aB0 + cxb1;
    const unsigned adA10 = adA00 + 65536, adA11 = adA01 + 65536;
    const unsigned adB00 = bB0 + cxb0, adB01 = bB0 + cxb1;
    const unsigned adB10 = adB00 + 65536, adB11 = adB01 + 65536;

    f32x4 acc[8][4] = {};
    float4 aLo[4][2], aHi[4][2], bC0[2][2], bC1[2][2];

    auto stage = [&](u16* dst, const u16* srcrow, int kt) {
        const u16* s = srcrow + (size_t)kt * 64;
        __builtin_amdgcn_global_load_lds((const AS1 void*)s, (AS3 void*)dst, 16, 0, 0);
        __builtin_amdgcn_global_load_lds((const AS1 void*)(s + (size_t)64 * K),
                                         (AS3 void*)(dst + 4096), 16, 0, 0);
    };

    stage(dB0h0, Bb, 0);  stage(dB0h1, BbH, 0);
    stage(dA0h0, Ab, 0);  stage(dA0h1, AbH, 0);
    stage(dB1h0, Bb, 1);  stage(dB1h1, BbH, 1);
    stage(dA1h0, Ab, 1);  stage(dA1h1, AbH, 1);
    asm volatile("s_waitcnt vmcnt(8)" ::: "memory");
    __builtin_amdgcn_s_barrier();
    RD_B4(bC0, adB00, adB01, "0", "2048");
    RD_B4(bC1, adB00, adB01, "4096", "6144");
    RD_A8(aLo, adA00, adA01, "0", "2048", "4096", "6144");

    const int niter = nkt >> 1;
    for (int i = 0; i < niter; ++i) {
        const int T = 2 * i;
        const int k2 = (T + 2 < nkt) ? T + 2 : nkt - 1;
        const int k3 = (T + 3 < nkt) ? T + 3 : nkt - 1;
        TILE_BODY(adA00, adA01, adA10, adA11, adB10, adB11,
                  dA0h0, dA0h1, dB0h0, dB0h1, k2);
        TILE_BODY(adA10, adA11, adA00, adA01, adB00, adB01,
                  dA1h0, dA1h1, dB1h0, dB1h1, k3);
    }

    asm volatile("s_waitcnt vmcnt(0) lgkmcnt(0)" ::: "memory");
    __builtin_amdgcn_s_barrier();

    float cb[4], cw[4];
    const bool isxc = (bcol < DINNER);
    if (isxc) {
        #pragma unroll
        for (int n = 0; n < 4; ++n) {
            const int cg = bcol + wn * 64 + n * 16 + lr;
            cb[n] = conv_b[cg]; cw[n] = conv_w[cg * 4 + 3];
        }
    }
    u16* eb = &lds[0][0][0];
    #pragma unroll
    for (int m = 0; m < 8; ++m)
        #pragma unroll
        for (int n = 0; n < 4; ++n)
            #pragma unroll
            for (int r = 0; r < 4; ++r) {
                const int rl = wm * 128 + m * 16 + l16 * 4 + r;
                const int cl = wn * 64 + n * 16 + lr;
                float v = acc[m][n][r];
                v = isxc ? silu_f(cb[n] + cw[n] * v) : silu_f(v);
                eb[rl * 256 + (cl ^ (((rl >> 2) & 3) << 4))] = f2bf(v);
            }
    __syncthreads();

    u16* base = isxc ? (dst0 + bcol) : (dst1 + (bcol - DINNER));
    #pragma unroll
    for (int it = 0; it < 16; ++it) {
        const int idx = it * 4096 + tid * 8;
        const int r = idx >> 8, c = idx & 255;
        uint4 v = *(const uint4*)(eb + r * 256 + (c ^ (((r >> 2) & 3) << 4)));
        *(uint4*)(base + (size_t)(brow + r) * DINNER + c) = v;
    }
}

// =============== fused GEMM2 + finish: xdb -> dtb (bf16) + s[b] ===============
// 256 blocks x 4 waves; block = 16 batch rows x full K=2048; waves split K
// (512 each) with PRIVATE double-buffered LDS slices (X[16][64] | W[96][64] =
// 14KB), staged via global_load_lds, self-paced counted vmcnt(14) -- no
// intra-loop barriers. End: barrier, cross-wave reduce (R7-verified), emit
// dtb + s. Removes Pxp roundtrip + finish kernel + one launch gap.
__global__ __launch_bounds__(256)
void gemm_xdb(const u16* __restrict__ xcb, const u16* __restrict__ Wx,
              u16* __restrict__ dtb, float* __restrict__ sbuf)
{
    __shared__ __align__(16) u16 slc[4][2][7168];   // 112KB
    const int t = threadIdx.x, w = t >> 6, l = t & 63;
    const int lr = l & 15, l16 = l >> 4;
    const int brow = blockIdx.x * 16;
    const int wk = w * 512;                          // wave's K-base

    auto stageX = [&](u16* dst, int step) {
        #pragma unroll
        for (int i = 0; i < 2; ++i) {
            const int o = i * 512 + l * 8;
            const int row = o >> 6;
            const int c8 = ((o >> 3) & 7) ^ (row & 7);
            __builtin_amdgcn_global_load_lds(
                (const AS1 void*)(xcb + (size_t)(brow + row) * DINNER + wk + step * 64 + c8 * 8),
                (AS3 void*)(dst + o), 16, 0, 0);
        }
    };
    auto stageW = [&](u16* dst, int step) {
        #pragma unroll
        for (int i = 0; i < 12; ++i) {
            const int o = i * 512 + l * 8;
            const int row = o >> 6;
            const int c8 = ((o >> 3) & 7) ^ (row & 7);
            __builtin_amdgcn_global_load_lds(
                (const AS1 void*)(Wx + (size_t)row * DINNER + wk + step * 64 + c8 * 8),
                (AS3 void*)(dst + 1024 + o), 16, 0, 0);
        }
    };

    f32x4 acc[6] = {};

    stageX(&slc[w][0][0], 0); stageW(&slc[w][0][0], 0);
    stageX(&slc[w][1][0], 1); stageW(&slc[w][1][0], 1);
    asm volatile("s_waitcnt vmcnt(14)" ::: "memory");
    __builtin_amdgcn_sched_barrier(0);

    for (int s = 0; s < 8; ++s) {
        const u16* sl = &slc[w][s & 1][0];
        #pragma unroll
        for (int kk = 0; kk < 2; ++kk) {
            bf16x8 av = *(const bf16x8*)(sl + lr * 64 + (((kk * 4 + l16) ^ (lr & 7)) * 8));
            #pragma unroll
            for (int n = 0; n < 6; ++n) {
                const int rb = n * 16 + lr;
                bf16x8 bv = *(const bf16x8*)(sl + 1024 + rb * 64 + (((kk * 4 + l16) ^ (rb & 7)) * 8));
                acc[n] = __builtin_amdgcn_mfma_f32_16x16x32_bf16(av, bv, acc[n], 0, 0, 0);
            }
        }
        __builtin_amdgcn_sched_barrier(0);
        const int s2 = (s + 2 < 8) ? s + 2 : 7;
        u16* dst = &slc[w][s & 1][0];
        stageX(dst, s2); stageW(dst, s2);
        asm volatile("s_waitcnt vmcnt(14)" ::: "memory");
        __builtin_amdgcn_sched_barrier(0);
    }

    asm volatile("s_waitcnt vmcnt(0)" ::: "memory");
    __syncthreads();

    // cross-wave reduce in LDS (region aliases wave slices -- all DMA drained)
    float* red = (float*)&slc[0][0][0];              // 4*16*96 f32 = 24KB
    #pragma unroll
    for (int n = 0; n < 6; ++n)
        #pragma unroll
        for (int r = 0; r < 4; ++r)
            red[w * 1536 + (l16 * 4 + r) * 96 + n * 16 + lr] = acc[n][r];
    __syncthreads();
    #pragma unroll
    for (int i = 0; i < 6; ++i) {
        const int idx = i * 256 + t;
        float v = red[idx] + red[1536 + idx] + red[3072 + idx] + red[4608 + idx];
        red[idx] = v;
        const int row = idx / 96, col = idx - row * 96;
        if (col < 64) dtb[(size_t)(brow + row) * 64 + col] = f2bf(v);
    }
    __syncthreads();
    if (t < 16) {
        float s = 0.f;
        #pragma unroll
        for (int n = 0; n < 16; ++n)
            s += red[t * 96 + 64 + n] * red[t * 96 + 80 + n];
        sbuf[brow + t] = s;
    }
}

// ---------------- GEMM3 + y epilogue (vectorized via bf16-dt LDS bounce) ----------------
__global__ __launch_bounds__(256)
void gemm_dt_y(const u16* __restrict__ dtb, const u16* __restrict__ Wdt,
               const float* __restrict__ b_dt, const float* __restrict__ Dskip,
               const float* __restrict__ sbuf,
               const u16* __restrict__ xcb, const u16* __restrict__ szb,
               u16* __restrict__ y)
{
    __shared__ __align__(16) u16 Ds[64 * 64];
    __shared__ __align__(16) u16 Ws[128 * 64];
    __shared__ __align__(16) u16 dts[64 * 128];
    const int t = threadIdx.x, w = t >> 6, l = t & 63;
    const int wr = w >> 1, wc = w & 1;
    const int brow = blockIdx.y * 64;
    const int bcol = blockIdx.x * 128;
    const int lr = l & 15, l16 = l >> 4;
    const int skk = ((l & 7) ^ (l >> 3)) * 8;

    {
        const u16* Dbase = dtb + (size_t)(brow + (l >> 3)) * 64 + skk;
        const u16* Wbase = Wdt + (size_t)(bcol + (l >> 3)) * 64 + skk;
        #pragma unroll
        for (int c = 0; c < 2; ++c) {
            const int seg = c * 4 + w;
            __builtin_amdgcn_global_load_lds(
                (const AS1 void*)(Dbase + (size_t)seg * 8 * 64),
                (AS3 void*)(&Ds[seg * 512]), 16, 0, 0);
        }
        #pragma unroll
        for (int c = 0; c < 4; ++c) {
            const int seg = c * 4 + w;
            __builtin_amdgcn_global_load_lds(
                (const AS1 void*)(Wbase + (size_t)seg * 8 * 64),
                (AS3 void*)(&Ws[seg * 512]), 16, 0, 0);
        }
    }
    __syncthreads();

    f32x4 acc[2][4] = {};
    #pragma unroll
    for (int kk = 0; kk < 2; ++kk) {
        bf16x8 av[2], bv[4];
        #pragma unroll
        for (int m = 0; m < 2; ++m) {
            const int r = wr * 32 + m * 16 + lr;
            av[m] = *(const bf16x8*)(&Ds[r * 64 + (((kk * 4 + l16) ^ (r & 7)) * 8)]);
        }
        #pragma unroll
        for (int n = 0; n < 4; ++n) {
            const int r = wc * 64 + n * 16 + lr;
            bv[n] = *(const bf16x8*)(&Ws[r * 64 + (((kk * 4 + l16) ^ (r & 7)) * 8)]);
        }
        #pragma unroll
        for (int m = 0; m < 2; ++m)
            #pragma unroll
            for (int n = 0; n < 4; ++n)
                acc[m][n] = __builtin_amdgcn_mfma_f32_16x16x32_bf16(av[m], bv[n], acc[m][n], 0, 0, 0);
    }

    #pragma unroll
    for (int m = 0; m < 2; ++m)
        #pragma unroll
        for (int n = 0; n < 4; ++n)
            #pragma unroll
            for (int r = 0; r < 4; ++r) {
                const int row = wr * 32 + m * 16 + l16 * 4 + r;
                const int col = wc * 64 + n * 16 + lr;
                float v = acc[m][n][r] + b_dt[bcol + col];
                float dt = (v > 20.f) ? v : log1pf(__expf(v));
                dts[row * 128 + (col ^ ((row & 7) << 4))] = f2bf(dt);
            }
    __syncthreads();

    const int rlo = t >> 4;
    const int cg  = (t & 15) * 8;
    #pragma unroll
    for (int rr = 0; rr < 4; ++rr) {
        const int row = rr * 16 + rlo;
        const int grow = brow + row;
        const float sr = sbuf[grow];
        uint4 dv = *(const uint4*)(&dts[row * 128 + ((cg ^ ((row & 7) << 4)))]);
        uint4 xv = *(const uint4*)(xcb + (size_t)grow * DINNER + bcol + cg);
        uint4 zv = *(const uint4*)(szb + (size_t)grow * DINNER + bcol + cg);
        float4 D0 = *(const float4*)(Dskip + bcol + cg);
        float4 D1 = *(const float4*)(Dskip + bcol + cg + 4);
        const float* Dp = &D0.x;
        uint4 ov;
        unsigned* op = (unsigned*)&ov;
        #pragma unroll
        for (int k = 0; k < 4; ++k) {
            unsigned du = ((const unsigned*)&dv)[k];
            unsigned xu = ((const unsigned*)&xv)[k];
            unsigned zu = ((const unsigned*)&zv)[k];
            float Da = (k < 2) ? Dp[2 * k]     : (&D1.x)[2 * (k - 2)];
            float Db = (k < 2) ? Dp[2 * k + 1] : (&D1.x)[2 * (k - 2) + 1];
            float y0 = (bf2f((u16)du) * sr + Da) * bf2f((u16)xu) * bf2f((u16)zu);
            float y1 = (bf2f((u16)(du >> 16)) * sr + Db) * bf2f((u16)(xu >> 16)) * bf2f((u16)(zu >> 16));
            op[k] = (unsigned)f2bf(y0) | ((unsigned)f2bf(y1) << 16);
        }
        *(uint4*)(y + (size_t)grow * DINNER + bcol + cg) = ov;
    }
}

// =============== GEMM4: 64x128 tile, direct fp32 out, dbuf counted vmcnt ===============
__global__ __launch_bounds__(256, 2)
void gemm4n(const u16* __restrict__ A, const u16* __restrict__ Bm,
            float* __restrict__ out)
{
    __shared__ __align__(16) u16 lds[2][12288];
    const int t = threadIdx.x, w = t >> 6, l = t & 63;
    const int wr = w >> 1, wc = w & 1;
    const int lr = l & 15, l16 = l >> 4;

    const int lin = blockIdx.y * 8 + blockIdx.x;
    const int xcd = lin & 7, q = lin >> 3;
    const int by = xcd * 8 + (q >> 3);
    const int bx = q & 7;
    const int brow = by * 64, bcol = bx * 128;
    const int K = DINNER, nkt = 32;

    auto stage = [&](int buf, int kt) {
        #pragma unroll
        for (int c = 0; c < 2; ++c) {
            const int o = c * 256 + t;
            const int sr = o >> 3;
            const int sc = (o & 7) ^ (sr & 7);
            __builtin_amdgcn_global_load_lds(
                (const AS1 void*)(A + (size_t)(brow + sr) * K + kt * 64 + sc * 8),
                (AS3 void*)(&lds[buf][o * 8]), 16, 0, 0);
        }
        #pragma unroll
        for (int c = 0; c < 4; ++c) {
            const int o = c * 256 + t;
            const int sr = o >> 3;
            const int sc = (o & 7) ^ (sr & 7);
            __builtin_amdgcn_global_load_lds(
                (const AS1 void*)(Bm + (size_t)(bcol + sr) * K + kt * 64 + sc * 8),
                (AS3 void*)(&lds[buf][4096 + o * 8]), 16, 0, 0);
        }
    };

    f32x4 acc[2][4] = {};

    stage(0, 0);
    stage(1, 1);
    asm volatile("s_waitcnt vmcnt(6)" ::: "memory");
    __builtin_amdgcn_s_barrier();

    for (int kt = 0; kt < nkt; ++kt) {
        const int cur = kt & 1;
        #pragma unroll
        for (int kk = 0; kk < 2; ++kk) {
            bf16x8 af[2], bf[4];
            #pragma unroll
            for (int m = 0; m < 2; ++m) {
                const int r = wr * 32 + m * 16 + lr;
                af[m] = *(const bf16x8*)(&lds[cur][r * 64 + (((kk * 4 + l16) ^ (r & 7)) * 8)]);
            }
            #pragma unroll
            for (int n = 0; n < 4; ++n) {
                const int r = wc * 64 + n * 16 + lr;
                bf[n] = *(const bf16x8*)(&lds[cur][4096 + r * 64 + (((kk * 4 + l16) ^ (r & 7)) * 8)]);
            }
            #pragma unroll
            for (int m = 0; m < 2; ++m)
                #pragma unroll
                for (int n = 0; n < 4; ++n)
                    acc[m][n] = __builtin_amdgcn_mfma_f32_16x16x32_bf16(af[m], bf[n], acc[m][n], 0, 0, 0);
        }
        __builtin_amdgcn_sched_barrier(0);
        __builtin_amdgcn_s_barrier();
        const int t2 = (kt + 2 < nkt) ? kt + 2 : nkt - 1;
        stage(cur, t2);
        asm volatile("s_waitcnt vmcnt(6)" ::: "memory");
        __builtin_amdgcn_sched_barrier(0);
        __builtin_amdgcn_s_barrier();
    }

    asm volatile("s_waitcnt vmcnt(0) lgkmcnt(0)" ::: "memory");
    __builtin_amdgcn_s_barrier();

    float* eb = (float*)&lds[0][0];
    #pragma unroll
    for (int m = 0; m < 2; ++m)
        #pragma unroll
        for (int n = 0; n < 4; ++n)
            #pragma unroll
            for (int r = 0; r < 4; ++r) {
                const int row = wr * 32 + m * 16 + l16 * 4 + r;
                const int col = wc * 64 + n * 16 + lr;
                eb[row * 128 + (col ^ ((row & 7) << 2))] = acc[m][n][r];
            }
    __syncthreads();
    #pragma unroll
    for (int it = 0; it < 8; ++it) {
        const int idx = it * 1024 + t * 4;
        const int row = idx >> 7, col = idx & 127;
        float4 v = *(const float4*)(eb + row * 128 + ((col ^ ((row & 7) << 2))));
        *(float4*)(out + (size_t)(brow + row) * DIM + bcol + col) = v;
    }
}

extern "C" void kernel_launch(void* const* d_in, const int* in_sizes, int n_in,
                              void* d_out, int out_size, void* d_ws, size_t ws_size,
                              hipStream_t stream) {
    const float* x      = (const float*)d_in[0];
    const float* ln_g   = (const float*)d_in[1];
    const float* ln_b   = (const float*)d_in[2];
    const float* W_in   = (const float*)d_in[3];
    const float* conv_w = (const float*)d_in[4];
    const float* conv_b = (const float*)d_in[5];
    const float* W_xp   = (const float*)d_in[6];
    const float* W_dt   = (const float*)d_in[7];
    const float* b_dt   = (const float*)d_in[8];
    // d_in[9] = A_log : dead (L=1, h0=0)
    const float* Dskip  = (const float*)d_in[10];
    const float* W_out  = (const float*)d_in[11];
    float* out = (float*)d_out;

    char* ws = (char*)d_ws;
    const size_t MB = 1u << 20;
    u16*  W_in_b  = (u16*)(ws);                   // 8MB
    u16*  xn      = (u16*)(ws + 8 * MB);          // 8MB
    u16*  xcb     = (u16*)(ws + 16 * MB);         // 16MB
    u16*  szb     = (u16*)(ws + 32 * MB);         // 16MB
    u16*  W_xp_b  = (u16*)(ws + 55 * MB);         // 384KB
    u16*  W_dt_b  = (u16*)(ws + 56 * MB);         // 256KB
    u16*  dtb     = (u16*)(ws + 57 * MB);         // 512KB
    float* sbuf   = (float*)(ws + 58 * MB);       // 16KB
    u16*  W_out_b = (u16*)(ws + 64 * MB);         // 4MB
    u16*  yb      = (u16*)(ws + 68 * MB);         // 16MB

    // 1) weight cvt + LN
    cvt_ln<<<BATCH + 2048, 256, 0, stream>>>(
        x, ln_g, ln_b, xn,
        (const float4*)W_in,  (ushort4*)W_in_b,  (2 * DINNER * DIM) / 4,
        (const float4*)W_out, (ushort4*)W_out_b, (DIM * DINNER) / 4,
        (const float4*)W_xp,  (ushort4*)W_xp_b,  (96 * DINNER) / 4,
        (const float4*)W_dt,  (ushort4*)W_dt_b,  (DINNER * 64) / 4);

    // 2) GEMM1: xz = xn @ W_in^T (fused conv+silu -> xc, sz)
    gemmP<<<dim3(4096 / 256, BATCH / 256, 1), 512, 0, stream>>>(
        xn, W_in_b, 4096, DIM, DIM / 64, xcb, szb, conv_w, conv_b);

    // 3) fused GEMM2 + finish: dtb + s
    gemm_xdb<<<BATCH / 16, 256, 0, stream>>>(xcb, W_xp_b, dtb, sbuf);

    // 4) GEMM3 + epilogue: y
    gemm_dt_y<<<dim3(DINNER / 128, BATCH / 64), 256, 0, stream>>>(
        dtb, W_dt_b, b_dt, Dskip, sbuf, xcb, szb, yb);

    // 5) GEMM4: out = y @ W_out^T (direct fp32, 64x128 tiles)
    gemm4n<<<dim3(DIM / 128, BATCH / 64), 256, 0, stream>>>(yb, W_out_b, out);
}